// Round 5
// baseline (88.906 us; speedup 1.0000x reference)
//
#include <hip/hip_runtime.h>
#include <hip/hip_bf16.h>
#include <math.h>

// SemiCRF dense span scores, MI355X gfx950.  Round 4 structure:
// per block (8 i's): vectorized stage x -> local prefix sums c1/c2 in LDS ->
// per-tile agg fragments built ENTIRELY IN REGISTERS (custom k-map: each lane's
// B-frag elems are exactly the mean/var quads it computes; W1 A-frag uses the
// SAME map, so HW k-pairing cancels) -> mfma(W1^T, agg) -> f32 epilogue.
// No agg LDS writes, no frag re-reads, no fences. c-base rows hoisted to regs.

typedef __attribute__((ext_vector_type(4))) float f32x4;
typedef __attribute__((ext_vector_type(8))) short bf16x8;
typedef __attribute__((ext_vector_type(4))) unsigned int u32x4;

#define L_SEQ 8192
#define F_DIM 26
#define SEG 100
#define HID 64
#define BI 8
#define REG_ROWS (BI + SEG - 1)            /* 107 x-rows per block */
#define C_ROWS (REG_ROWS + 1)              /* 108 prefix entries   */
#define C_STRIDE 28                        /* f32 per c-row (16B-multiple) */
#define C_BYTES (C_ROWS * C_STRIDE * 4)    /* 12096 */
#define LUT_OFF (2 * C_BYTES)              /* 24192 */
#define LUT_N 112                          /* len/loglen, covers junk l<=112 */
#define XS_OFF (LUT_OFF + LUT_N * 4)       /* 24640 */
#define XS_ELEMS 2784                      /* 107*26=2782, padded to quad */
#define SMEM_BYTES (XS_OFF + XS_ELEMS * 4) /* 35776 -> 4 blocks/CU */

__device__ __forceinline__ unsigned short f2bf(float v) {   // setup-only path
    unsigned u = __builtin_bit_cast(unsigned, v);
    u += 0x7FFFu + ((u >> 16) & 1u);   // round-to-nearest-even
    return (unsigned short)(u >> 16);
}
__device__ __forceinline__ unsigned pk(unsigned short a, unsigned short b) {
    return (unsigned)a | ((unsigned)b << 16);
}
__device__ __forceinline__ unsigned cvtpk(float lo, float hi) {  // hot path
    unsigned r;
    asm("v_cvt_pk_bf16_f32 %0, %1, %2" : "=v"(r) : "v"(lo), "v"(hi));
    return r;
}

__global__ __launch_bounds__(256, 4)
void semicrf_kernel(const float* __restrict__ x, const float* __restrict__ W1,
                    const float* __restrict__ b1, const float* __restrict__ W2,
                    const float* __restrict__ b2, float* __restrict__ out) {
    __shared__ __align__(16) char smem[SMEM_BYTES];
    float*    c1    = (float*)smem;
    float*    c2    = (float*)(smem + C_BYTES);
    unsigned* lenlt = (unsigned*)(smem + LUT_OFF);
    float*    xs    = (float*)(smem + XS_OFF);

    const int tid = threadIdx.x;
    const int lane = tid & 63;
    const int wave = tid >> 6;
    const int i0 = blockIdx.x * BI;

    // ---- stage x rows [i0, i0+107) into LDS, f32x4, zero-padded past L ----
    {
        const int base = i0 * F_DIM;          // 16B-aligned (i0*104 bytes)
        for (int e = tid; e < XS_ELEMS / 4; e += 256) {
            const int g = base + 4 * e;
            f32x4 v;
            if (g + 3 < L_SEQ * F_DIM) {
                v = *(const f32x4*)(x + g);
            } else {
#pragma unroll
                for (int k = 0; k < 4; ++k)
                    v[k] = (g + k < L_SEQ * F_DIM) ? x[g + k] : 0.0f;
            }
            if (4 * e + 3 >= XS_ELEMS - 2) { v[2] = 0.0f; v[3] = 0.0f; } // pad tail
            *(f32x4*)(xs + 4 * e) = v;
        }
    }
    // ---- len/loglen LUT (once per block) ----
    if (tid < LUT_N) {
        float lf = (float)(tid + 1);
        lenlt[tid] = pk(f2bf(lf * 0.002f), f2bf(logf(lf + 1e-6f) * (1.0f / 6.0f)));
    }

    // ---- per-lane W1^T fragments (A-operand), custom k-map, + b1/W2 quads ---
    // k-map (lane q = lane>>4, elem j), s=0 -> a0, s=1 -> a1:
    //  q<3 : j<4 -> f=4q+j ; j>=4 -> f=16+4q+(j-4)   (f>=26 -> zero weight)
    //        s=0: mean_f (wr=f), s=1: var_f (wr=26+f)
    //  q=3 : j<4 -> f=12+j (mean/var as above); s=0 j=4 -> len (wr=52),
    //        s=0 j=5 -> loglen (wr=53); all else zero.
    const int r = lane & 15;   // A row (hid low) / B col (seg_row) / D col
    const int q = lane >> 4;
    bf16x8 wfrag[2][4];
#pragma unroll
    for (int s = 0; s < 2; ++s) {
#pragma unroll
        for (int t = 0; t < 4; ++t) {
            bf16x8 v;
#pragma unroll
            for (int j = 0; j < 8; ++j) {
                int wr = -1;
                if (q < 3 || j < 4) {
                    int f = (j < 4) ? (4 * q + j) : (16 + 4 * q + (j - 4));
                    if (f < 26) wr = (s == 0) ? f : 26 + f;
                } else if (s == 0 && j == 4) wr = 52;
                else if (s == 0 && j == 5) wr = 53;
                float wv = (wr >= 0) ? W1[wr * HID + (t * 16 + r)] : 0.0f;
                v[j] = (short)f2bf(wv);
            }
            wfrag[s][t] = v;
        }
    }
    // D[row=hid t*16+q*4+g][col=seg_row r] -> this lane needs b1/W2 at q*4+g
    f32x4 b1v[4], w2v[4];
#pragma unroll
    for (int t = 0; t < 4; ++t) {
        b1v[t] = *(const f32x4*)(b1 + t * 16 + q * 4);
        w2v[t] = *(const f32x4*)(W2 + t * 16 + q * 4);
    }
    const float b2v = b2[0];

    __syncthreads();

    // ---- local prefix sums (28 scan lanes of wave 0; cols 26,27 == 0) ----
    if (tid < C_STRIDE) {
        const int f = tid;
        float s1 = 0.0f, s2 = 0.0f;
        c1[f] = 0.0f;
        c2[f] = 0.0f;
#pragma unroll 4
        for (int rr = 0; rr < REG_ROWS; ++rr) {
            float xv = (f < F_DIM) ? xs[rr * F_DIM + f] : 0.0f;
            s1 += xv;
            s2 = fmaf(xv, xv, s2);
            c1[(rr + 1) * C_STRIDE + f] = s1;
            c2[(rr + 1) * C_STRIDE + f] = s2;
        }
    }
    __syncthreads();

    // ---- main loop: 2 i's per wave x 7 l-chunks, agg frags in registers ----
    const int f0A = 4 * q;
    const int f0B = 16 + 4 * q;                // used only when q < 3

    for (int bih = 0; bih < 2; ++bih) {
        const int bi = wave + 4 * bih;
        const int i = i0 + bi;
        // hoist base-row prefix quads for this i into registers
        const float* c1b = c1 + bi * C_STRIDE;
        const float* c2b = c2 + bi * C_STRIDE;
        const f32x4 c1iA = *(const f32x4*)(c1b + f0A);
        const f32x4 c2iA = *(const f32x4*)(c2b + f0A);
        f32x4 c1iB = {0.f, 0.f, 0.f, 0.f}, c2iB = {0.f, 0.f, 0.f, 0.f};
        if (q < 3) {
            c1iB = *(const f32x4*)(c1b + f0B);
            c2iB = *(const f32x4*)(c2b + f0B);
        }

        for (int lc = 0; lc < 7; ++lc) {
            const int l_seg = lc * 16 + 1 + r;          // this lane's length
            const float inv_l = __builtin_amdgcn_rcpf((float)l_seg);
            const int cj = min(bi + l_seg, REG_ROWS);   // clamp junk (l>100)
            const float* c1j = c1 + cj * C_STRIDE;
            const float* c2j = c2 + cj * C_STRIDE;

            union { u32x4 u; bf16x8 h; } A0, A1;
            {   // quad A: f = f0A..f0A+3  (all lanes)
                f32x4 m = (*(const f32x4*)(c1j + f0A) - c1iA) * inv_l;
                f32x4 t = (*(const f32x4*)(c2j + f0A) - c2iA) * inv_l;
                f32x4 v = t - m * m;
                A0.u.x = cvtpk(m[0], m[1]);
                A0.u.y = cvtpk(m[2], m[3]);
                A1.u.x = cvtpk(v[0], v[1]);
                A1.u.y = cvtpk(v[2], v[3]);
            }
            if (q < 3) {   // quad B: f = f0B..f0B+3 (f 26,27 are zero cols)
                f32x4 m = (*(const f32x4*)(c1j + f0B) - c1iB) * inv_l;
                f32x4 t = (*(const f32x4*)(c2j + f0B) - c2iB) * inv_l;
                f32x4 v = t - m * m;
                A0.u.z = cvtpk(m[0], m[1]);
                A0.u.w = cvtpk(m[2], m[3]);
                A1.u.z = cvtpk(v[0], v[1]);
                A1.u.w = cvtpk(v[2], v[3]);
            } else {       // len/loglen in a0 elems 4,5; rest zero
                A0.u.z = lenlt[l_seg - 1];
                A0.u.w = 0u;
                A1.u.z = 0u;
                A1.u.w = 0u;
            }

            f32x4 acc0 = b1v[0], acc1 = b1v[1], acc2 = b1v[2], acc3 = b1v[3];
            acc0 = __builtin_amdgcn_mfma_f32_16x16x32_bf16(wfrag[0][0], A0.h, acc0, 0, 0, 0);
            acc1 = __builtin_amdgcn_mfma_f32_16x16x32_bf16(wfrag[0][1], A0.h, acc1, 0, 0, 0);
            acc2 = __builtin_amdgcn_mfma_f32_16x16x32_bf16(wfrag[0][2], A0.h, acc2, 0, 0, 0);
            acc3 = __builtin_amdgcn_mfma_f32_16x16x32_bf16(wfrag[0][3], A0.h, acc3, 0, 0, 0);
            acc0 = __builtin_amdgcn_mfma_f32_16x16x32_bf16(wfrag[1][0], A1.h, acc0, 0, 0, 0);
            acc1 = __builtin_amdgcn_mfma_f32_16x16x32_bf16(wfrag[1][1], A1.h, acc1, 0, 0, 0);
            acc2 = __builtin_amdgcn_mfma_f32_16x16x32_bf16(wfrag[1][2], A1.h, acc2, 0, 0, 0);
            acc3 = __builtin_amdgcn_mfma_f32_16x16x32_bf16(wfrag[1][3], A1.h, acc3, 0, 0, 0);

            // epilogue: p = sum_t sum_g relu(h) * w2 (b1 folded into C-init)
            float p0 = 0.f, p1 = 0.f, p2 = 0.f, p3 = 0.f;
#define EPI(ACC, PT, T)                                             \
            PT = fmaf(fmaxf(ACC[0], 0.f), w2v[T][0], PT);           \
            PT = fmaf(fmaxf(ACC[1], 0.f), w2v[T][1], PT);           \
            PT = fmaf(fmaxf(ACC[2], 0.f), w2v[T][2], PT);           \
            PT = fmaf(fmaxf(ACC[3], 0.f), w2v[T][3], PT);
            EPI(acc0, p0, 0) EPI(acc1, p1, 1) EPI(acc2, p2, 2) EPI(acc3, p3, 3)
#undef EPI
            float p = (p0 + p1) + (p2 + p3);
            p += __shfl_xor(p, 16);            // reduce over q (4 k-groups)
            p += __shfl_xor(p, 32);

            if (lane < 16) {                   // one lane per seg_row
                const int l = lc * 16 + 1 + r;
                if (l <= SEG)
                    out[i * SEG + (l - 1)] = (i + l <= L_SEQ) ? p + b2v : 0.0f;
            }
        }
    }
}

extern "C" void kernel_launch(void* const* d_in, const int* in_sizes, int n_in,
                              void* d_out, int out_size, void* d_ws, size_t ws_size,
                              hipStream_t stream) {
    const float* x  = (const float*)d_in[0];
    const float* W1 = (const float*)d_in[1];
    const float* b1 = (const float*)d_in[2];
    const float* W2 = (const float*)d_in[3];
    const float* b2 = (const float*)d_in[4];
    float* out = (float*)d_out;
    semicrf_kernel<<<dim3(L_SEQ / BI), dim3(256), 0, stream>>>(x, W1, b1, W2, b2, out);
}